// Round 2
// baseline (237.365 us; speedup 1.0000x reference)
//
#include <hip/hip_runtime.h>
#include <hip/hip_fp16.h>
#include <math.h>

#define C 128
#define HB 2048          // score histogram buckets (top 11 bits of ordered float)
#define NS 4096          // candidate capacity (pow2 for bitonic)
#define SHB 192          // score/hist blocks inside k_front
#define BCAP 6144        // k_bin LDS edge cache capacity (avg bin ~4082, +32 sigma)

typedef __attribute__((ext_vector_type(8))) short bf16x8;
typedef __attribute__((ext_vector_type(4))) float f32x4;

__device__ inline unsigned ord_f32(float f) {
    unsigned u = __float_as_uint(f);
    return u ^ ((u & 0x80000000u) ? 0xFFFFFFFFu : 0x80000000u);
}
__device__ inline float unord_f32(unsigned u) {
    return __uint_as_float(u ^ ((u & 0x80000000u) ? 0x80000000u : 0xFFFFFFFFu));
}
__device__ inline short f2bf(float f) {        // RNE float -> bf16 bits
    unsigned u = __float_as_uint(f);
    return (short)((u + 0x7FFFu + ((u >> 16) & 1u)) >> 16);
}
__device__ inline float bf2f(short s) {
    return __uint_as_float(((unsigned)(unsigned short)s) << 16);
}

// ---------------------------------------------------------------- front: blocks [0,SHB) scores+hist; rest: MSD edge hist
__global__ __launch_bounds__(1024) void k_front(const float* __restrict__ X,
                                                const float* __restrict__ p,
                                                float* __restrict__ scores,
                                                int* __restrict__ hist,
                                                const int* __restrict__ ei,
                                                int* __restrict__ rh,
                                                int N, int E, int NBIN, int NBLKE) {
    int t = threadIdx.x;
    if (blockIdx.x < SHB) {
        __shared__ int lh[HB];
        for (int i = t; i < HB; i += 1024) lh[i] = 0;
        __syncthreads();
        int gw   = blockIdx.x * 16 + (t >> 6);     // SHB*16 waves total
        int lane = t & 63;
        const float2* p2 = (const float2*)p;
        float2 pv2 = p2[lane];
        for (int r = gw; r < N; r += SHB * 16) {
            const float2* xr = (const float2*)(X + (size_t)r * C);
            float2 x2 = xr[lane];
            float a = x2.x * pv2.x + x2.y * pv2.y;
            #pragma unroll
            for (int o = 32; o; o >>= 1) a += __shfl_down(a, o);
            if (lane == 0) {
                scores[r] = a;
                atomicAdd(&lh[ord_f32(a) >> 21], 1);
            }
        }
        __syncthreads();
        for (int i = t; i < HB; i += 1024) {
            int v = lh[i];
            if (v) atomicAdd(&hist[i], v);
        }
    } else {
        __shared__ int bh[8][256];                 // wave-pair private sub-histograms
        int cp = (t >> 7) & 7;
        for (int i = t; i < 8 * 256; i += 1024) ((int*)bh)[i] = 0;
        __syncthreads();
        int eb = blockIdx.x - SHB;
        int e = eb * 2048 + t * 2;
        if (e + 1 < E) {
            int2 d2 = *(const int2*)(ei + E + e);
            atomicAdd(&bh[cp][d2.x >> 8], 1);
            atomicAdd(&bh[cp][d2.y >> 8], 1);
        } else if (e < E) {
            atomicAdd(&bh[cp][ei[E + e] >> 8], 1);
        }
        __syncthreads();
        for (int i = t; i < NBIN; i += 1024) {
            int s = 0;
            #pragma unroll
            for (int c = 0; c < 8; c++) s += bh[c][i];
            rh[(size_t)i * NBLKE + eb] = s;
        }
    }
}

// ---------------------------------------------------------------- fused filter + topk select (single block)
__global__ __launch_bounds__(1024) void k_fsel(const float* __restrict__ scores,
                                               const int* __restrict__ hist,
                                               const float* __restrict__ p,
                                               int* __restrict__ tidx, float* __restrict__ gate,
                                               int N) {
    __shared__ unsigned long long sk[NS];          // 32 KB candidate keys
    __shared__ int hsc[1024];
    __shared__ int sT;
    __shared__ int s_nc;
    __shared__ float red[16];
    __shared__ float s_pn;
    int t = threadIdx.x;
    // ---- threshold scan over descending buckets, 2 per thread
    int b0 = HB - 1 - 2 * t, b1 = HB - 2 - 2 * t;
    int l0 = hist[b0], l1 = hist[b1];
    int sum = l0 + l1;
    hsc[t] = sum;
    if (t == 0) s_nc = 0;
    __syncthreads();
    for (int off = 1; off < 1024; off <<= 1) {
        int v = (t >= off) ? hsc[t - off] : 0;
        __syncthreads();
        hsc[t] += v;
        __syncthreads();
    }
    int run = hsc[t] - sum;
    if (run < C && run + l0 >= C) sT = b0;
    if (run + l0 < C && run + l0 + l1 >= C) sT = b1;
    __syncthreads();
    int T = sT;
    // ---- filter scores into LDS candidates
    for (int i = t; i < N; i += 1024) {
        unsigned u = ord_f32(scores[i]);
        if ((int)(u >> 21) >= T) {
            int pos = atomicAdd(&s_nc, 1);
            if (pos < NS)
                sk[pos] = ((unsigned long long)u << 32) | (unsigned)(~(unsigned)i);
        }
    }
    // ---- ||p|| (overlaps with filter completion)
    float pv = 0.f;
    if (t < C) { float x = p[t]; pv = x * x; }
    #pragma unroll
    for (int o = 32; o; o >>= 1) pv += __shfl_down(pv, o);
    if ((t & 63) == 0) red[t >> 6] = pv;
    __syncthreads();                               // s_nc + red final
    if (t == 0) {
        float s = 0.f;
        for (int i = 0; i < 16; i++) s += red[i];
        s_pn = sqrtf(s);
    }
    int M = s_nc; if (M > NS) M = NS;
    int S = 256; while (S < M) S <<= 1;
    for (int i = t; i < S; i += 1024) if (i >= M) sk[i] = 0ULL;
    // ---- bitonic sort desc (first step's barrier covers padding + s_pn)
    for (int k = 2; k <= S; k <<= 1) {
        for (int j = k >> 1; j > 0; j >>= 1) {
            __syncthreads();
            for (int idx = t; idx < S; idx += 1024) {
                int l = idx ^ j;
                if (l > idx) {
                    unsigned long long a = sk[idx], b = sk[l];
                    bool desc = (idx & k) == 0;
                    if (desc ? (a < b) : (a > b)) { sk[idx] = b; sk[l] = a; }
                }
            }
        }
    }
    __syncthreads();
    if (t < C) {
        unsigned long long g = sk[t];
        tidx[t] = (int)(~(unsigned)(g & 0xFFFFFFFFull));
        gate[t] = tanhf(unord_f32((unsigned)(g >> 32)) / s_pn);
    }
}

// ---------------------------------------------------------------- radix scan A: per-bin exclusive scan over blocks
__global__ __launch_bounds__(512) void k_rscanA(int* __restrict__ rh, int* __restrict__ tot, int NBLKE) {
    __shared__ int sc[512];
    int t = threadIdx.x;
    int bin = blockIdx.x;
    int v = (t < NBLKE) ? rh[(size_t)bin * NBLKE + t] : 0;
    sc[t] = v;
    __syncthreads();
    for (int off = 1; off < 512; off <<= 1) {
        int u = (t >= off) ? sc[t - off] : 0;
        __syncthreads();
        sc[t] += u;
        __syncthreads();
    }
    if (t < NBLKE) rh[(size_t)bin * NBLKE + t] = sc[t] - v;
    if (t == 511) tot[bin] = sc[511];
}

// ---------------------------------------------------------------- radix scatter: edges -> dst buckets (LDS cursors only)
__global__ __launch_bounds__(1024) void k_rscat(const int* __restrict__ ei, const float* __restrict__ ew,
                                                const int* __restrict__ rh, const int* __restrict__ tot,
                                                unsigned long long* __restrict__ sorted,
                                                int E, int NBIN, int NBLKE) {
    __shared__ int sc[256];
    __shared__ int cur[256];
    int t = threadIdx.x;
    int eb = blockIdx.x;
    int v = 0;
    if (t < 256) {
        v = (t < NBIN) ? tot[t] : 0;
        sc[t] = v;
    }
    __syncthreads();
    for (int off = 1; off < 256; off <<= 1) {
        int u = (t < 256 && t >= off) ? sc[t - off] : 0;
        __syncthreads();
        if (t < 256) sc[t] += u;
        __syncthreads();
    }
    if (t < NBIN) cur[t] = (sc[t] - v) + rh[(size_t)t * NBLKE + eb];
    __syncthreads();
    int e = eb * 2048 + t * 2;
    #pragma unroll
    for (int j = 0; j < 2; j++) {
        int ee = e + j;
        if (ee < E) {
            int s = ei[ee], d = ei[E + ee];
            float w = ew[ee];
            int pos = atomicAdd(&cur[d >> 8], 1);
            unsigned long long pk = ((unsigned long long)(unsigned)d << 48)
                                  | ((unsigned long long)(unsigned short)s << 32)
                                  |  (unsigned long long)__float_as_uint(w);
            sorted[pos] = pk;
        }
    }
}

// ---------------------------------------------------------------- per-bucket: counting sort by dst&255 + offs/deg/dinv
// pass 1 caches the bin's edges in LDS so pass 2 avoids re-reading `sorted`
__global__ __launch_bounds__(1024) void k_bin(const unsigned long long* __restrict__ sorted,
                                              const int* __restrict__ tot,
                                              int* __restrict__ offs, float* __restrict__ dinv,
                                              unsigned* __restrict__ epack,
                                              int N, int E, int NBIN) {
    __shared__ unsigned long long ebuf[BCAP];      // 48 KB edge cache
    __shared__ int cnt[256];
    __shared__ float wsum[256];
    __shared__ int sc[256];
    __shared__ int cur2[256];
    __shared__ int s_base[2];
    int t = threadIdx.x;
    int b = blockIdx.x;
    // recompute bin base from tot
    int v = 0;
    if (t < 256) {
        v = (t < NBIN) ? tot[t] : 0;
        sc[t] = v;
    }
    __syncthreads();
    for (int off = 1; off < 256; off <<= 1) {
        int u = (t < 256 && t >= off) ? sc[t - off] : 0;
        __syncthreads();
        if (t < 256) sc[t] += u;
        __syncthreads();
    }
    if (t == b) { s_base[0] = sc[t] - v; s_base[1] = sc[t]; }
    __syncthreads();
    int s0 = s_base[0], s1 = s_base[1];
    for (int i = t; i < 256; i += 1024) { cnt[i] = 0; wsum[i] = 0.f; }
    __syncthreads();
    for (int i = s0 + t; i < s1; i += 1024) {
        unsigned long long pk = sorted[i];
        int li = i - s0;
        if (li < BCAP) ebuf[li] = pk;
        int d8 = (int)(pk >> 48) & 255;
        float w = __uint_as_float((unsigned)(pk & 0xFFFFFFFFull));
        atomicAdd(&cnt[d8], 1);
        atomicAdd(&wsum[d8], w);
    }
    __syncthreads();
    int cv = (t < 256) ? cnt[t] : 0;
    if (t < 256) sc[t] = cv;
    __syncthreads();
    for (int off = 1; off < 256; off <<= 1) {
        int u = (t < 256 && t >= off) ? sc[t - off] : 0;
        __syncthreads();
        if (t < 256) sc[t] += u;
        __syncthreads();
    }
    if (t < 256) {
        int loff = sc[t] - cv;
        cur2[t] = s0 + loff;
        int node = b * 256 + t;
        if (node < N) {
            offs[node] = s0 + loff;
            dinv[node] = rsqrtf(1.0f + wsum[t]);
        }
    }
    if (b == NBIN - 1 && t == 0) offs[N] = E;
    __syncthreads();
    for (int i = s0 + t; i < s1; i += 1024) {
        int li = i - s0;
        unsigned long long pk = (li < BCAP) ? ebuf[li] : sorted[i];
        int d8 = (int)(pk >> 48) & 255;
        unsigned src = (unsigned)((pk >> 32) & 0xFFFFu);
        float w = __uint_as_float((unsigned)(pk & 0xFFFFFFFFull));
        int pos = atomicAdd(&cur2[d8], 1);
        __half hw = __float2half(w);
        epack[pos] = ((unsigned)*(unsigned short*)&hw << 16) | src;
    }
}

// ---------------------------------------------------------------- GRU step (X_tilde folded in) -> W_new^T
__global__ __launch_bounds__(256) void k_gru(const float* __restrict__ X,
                                             const int* __restrict__ tidx,
                                             const float* __restrict__ gate,
                                             const float* __restrict__ Wc,
                                             const float* __restrict__ W_ih, const float* __restrict__ W_hh,
                                             const float* __restrict__ b_ih, const float* __restrict__ b_hh,
                                             float* __restrict__ wnewT) {
    int t = threadIdx.x;
    int i = t & 127;
    int j = blockIdx.x * 2 + (t >> 7);
    int src = tidx[i];
    float g = gate[i];
    const float4* xr   = (const float4*)(X + (size_t)src * C);
    const float4* hr   = (const float4*)(Wc + (size_t)i * C);
    const float4* wri  = (const float4*)(W_ih + (size_t)j * C);
    const float4* wzi  = (const float4*)(W_ih + (size_t)(C + j) * C);
    const float4* wni  = (const float4*)(W_ih + (size_t)(2 * C + j) * C);
    const float4* wrh  = (const float4*)(W_hh + (size_t)j * C);
    const float4* wzh  = (const float4*)(W_hh + (size_t)(C + j) * C);
    const float4* wnh  = (const float4*)(W_hh + (size_t)(2 * C + j) * C);
    float gir = 0, giz = 0, gin = 0, ghr = 0, ghz = 0, ghn = 0;
    #pragma unroll 8
    for (int k4 = 0; k4 < C / 4; k4++) {
        float4 x = xr[k4], h = hr[k4], a;
        a = wri[k4]; gir += x.x * a.x + x.y * a.y + x.z * a.z + x.w * a.w;
        a = wzi[k4]; giz += x.x * a.x + x.y * a.y + x.z * a.z + x.w * a.w;
        a = wni[k4]; gin += x.x * a.x + x.y * a.y + x.z * a.z + x.w * a.w;
        a = wrh[k4]; ghr += h.x * a.x + h.y * a.y + h.z * a.z + h.w * a.w;
        a = wzh[k4]; ghz += h.x * a.x + h.y * a.y + h.z * a.z + h.w * a.w;
        a = wnh[k4]; ghn += h.x * a.x + h.y * a.y + h.z * a.z + h.w * a.w;
    }
    gir = g * gir + b_ih[j];         ghr += b_hh[j];
    giz = g * giz + b_ih[C + j];     ghz += b_hh[C + j];
    gin = g * gin + b_ih[2 * C + j]; ghn += b_hh[2 * C + j];
    float r = 1.f / (1.f + expf(-(gir + ghr)));
    float z = 1.f / (1.f + expf(-(giz + ghz)));
    float n = tanhf(gin + r * ghn);
    float wn = (1.f - z) * n + z * Wc[(size_t)i * C + j];
    wnewT[(size_t)j * C + i] = wn;
}

// ---------------------------------------------------------------- Xw rows = dinv[r]*(X @ W_new^T)[r], stored fp16
__global__ __launch_bounds__(256) void k_xw(const float* __restrict__ X,
                                            const float* __restrict__ wnewT,
                                            const float* __restrict__ dinv,
                                            unsigned* __restrict__ xwh, int N) {
    __shared__ short Bh[C * C];
    __shared__ short Bl[C * C];
    int t = threadIdx.x;
    for (int idx = t; idx < C * C; idx += 256) {
        int k = idx >> 7, c = idx & 127;
        float wv = wnewT[idx];
        short hi = f2bf(wv);
        float lo = wv - bf2f(hi);
        int pos = c * C + (k ^ ((c & 15) << 3));
        Bh[pos] = hi;
        Bl[pos] = f2bf(lo);
    }
    __syncthreads();

    int wave = t >> 6, lane = t & 63;
    int ln = lane & 15, quad = lane >> 4;
    int r0 = blockIdx.x * 128 + wave * 32;

    f32x4 acc[2][8];
    #pragma unroll
    for (int mt = 0; mt < 2; mt++)
        #pragma unroll
        for (int ct = 0; ct < 8; ct++) { acc[mt][ct][0] = 0.f; acc[mt][ct][1] = 0.f; acc[mt][ct][2] = 0.f; acc[mt][ct][3] = 0.f; }

    int row0 = r0 + ln;       if (row0 >= N) row0 = N - 1;
    int row1 = r0 + 16 + ln;  if (row1 >= N) row1 = N - 1;
    const float* xr0 = X + (size_t)row0 * C + quad * 8;
    const float* xr1 = X + (size_t)row1 * C + quad * 8;

    for (int ks = 0; ks < 4; ks++) {
        float a0[8], a1[8];
        *(float4*)&a0[0] = *(const float4*)(xr0 + ks * 32);
        *(float4*)&a0[4] = *(const float4*)(xr0 + ks * 32 + 4);
        *(float4*)&a1[0] = *(const float4*)(xr1 + ks * 32);
        *(float4*)&a1[4] = *(const float4*)(xr1 + ks * 32 + 4);
        bf16x8 a0h, a0l, a1h, a1l;
        #pragma unroll
        for (int j = 0; j < 8; j++) {
            short h0 = f2bf(a0[j]); a0h[j] = h0; a0l[j] = f2bf(a0[j] - bf2f(h0));
            short h1 = f2bf(a1[j]); a1h[j] = h1; a1l[j] = f2bf(a1[j] - bf2f(h1));
        }
        int kb = ks * 32 + quad * 8;
        int koff = kb ^ (ln << 3);
        #pragma unroll
        for (int ct = 0; ct < 8; ct++) {
            int pos = (ct * 16 + ln) * C + koff;
            bf16x8 bh = *(bf16x8*)&Bh[pos];
            bf16x8 bl = *(bf16x8*)&Bl[pos];
            acc[0][ct] = __builtin_amdgcn_mfma_f32_16x16x32_bf16(a0h, bh, acc[0][ct], 0, 0, 0);
            acc[0][ct] = __builtin_amdgcn_mfma_f32_16x16x32_bf16(a0l, bh, acc[0][ct], 0, 0, 0);
            acc[0][ct] = __builtin_amdgcn_mfma_f32_16x16x32_bf16(a0h, bl, acc[0][ct], 0, 0, 0);
            acc[1][ct] = __builtin_amdgcn_mfma_f32_16x16x32_bf16(a1h, bh, acc[1][ct], 0, 0, 0);
            acc[1][ct] = __builtin_amdgcn_mfma_f32_16x16x32_bf16(a1l, bh, acc[1][ct], 0, 0, 0);
            acc[1][ct] = __builtin_amdgcn_mfma_f32_16x16x32_bf16(a1h, bl, acc[1][ct], 0, 0, 0);
        }
    }

    // D layout (m89): col = lane&15, row = quad*4 + reg; store half(dinv[r]*val)
    __half* H = (__half*)xwh;
    #pragma unroll
    for (int mt = 0; mt < 2; mt++) {
        int rbase = r0 + mt * 16 + quad * 4;
        #pragma unroll
        for (int reg = 0; reg < 4; reg++) {
            int r = rbase + reg;
            if (r < N) {
                float dvr = dinv[r];
                #pragma unroll
                for (int ct = 0; ct < 8; ct++) {
                    int col = ct * 16 + ln;
                    H[(size_t)r * C + col] = __float2half(acc[mt][ct][reg] * dvr);
                }
            }
        }
    }
}

// ---------------------------------------------------------------- gather: wave/node; rows premultiplied by dinv[src]
__global__ __launch_bounds__(256) void k_gather(const unsigned* __restrict__ xwh,
                                                const int* __restrict__ offs,
                                                const unsigned* __restrict__ epack,
                                                const float* __restrict__ dinv,
                                                const float* __restrict__ b_conv,
                                                float* __restrict__ out, int N) {
    int t = threadIdx.x;
    int v = blockIdx.x * 4 + (t >> 6);
    int lane = t & 63;
    if (v >= N) return;
    float dv = dinv[v];
    unsigned uv = xwh[(size_t)v * 64 + lane];
    __half2 hv = *(__half2*)&uv;
    float acc0 = __low2float(hv);
    float acc1 = __high2float(hv);
    int e0 = offs[v], e1 = offs[v + 1];
    int e = e0;
    for (; e + 15 < e1; e += 16) {
        unsigned pk[16], ux[16];
        #pragma unroll
        for (int j = 0; j < 16; j++) pk[j] = __builtin_nontemporal_load(&epack[e + j]);
        #pragma unroll
        for (int j = 0; j < 16; j++) ux[j] = xwh[(size_t)(pk[j] & 0xFFFFu) * 64 + lane];
        #pragma unroll
        for (int j = 0; j < 16; j++) {
            unsigned short hs = (unsigned short)(pk[j] >> 16);
            float nm = __half2float(*(__half*)&hs);
            __half2 h = *(__half2*)&ux[j];
            acc0 += nm * __low2float(h);
            acc1 += nm * __high2float(h);
        }
    }
    for (; e + 3 < e1; e += 4) {
        unsigned pk[4], ux[4];
        #pragma unroll
        for (int j = 0; j < 4; j++) pk[j] = __builtin_nontemporal_load(&epack[e + j]);
        #pragma unroll
        for (int j = 0; j < 4; j++) ux[j] = xwh[(size_t)(pk[j] & 0xFFFFu) * 64 + lane];
        #pragma unroll
        for (int j = 0; j < 4; j++) {
            unsigned short hs = (unsigned short)(pk[j] >> 16);
            float nm = __half2float(*(__half*)&hs);
            __half2 h = *(__half2*)&ux[j];
            acc0 += nm * __low2float(h);
            acc1 += nm * __high2float(h);
        }
    }
    for (; e < e1; e++) {
        unsigned pA = __builtin_nontemporal_load(&epack[e]);
        unsigned uA = xwh[(size_t)(pA & 0xFFFFu) * 64 + lane];
        unsigned short hs = (unsigned short)(pA >> 16);
        float nA = __half2float(*(__half*)&hs);
        __half2 hA = *(__half2*)&uA;
        acc0 += nA * __low2float(hA);
        acc1 += nA * __high2float(hA);
    }
    const float2* b2 = (const float2*)b_conv;
    float2 bb = b2[lane];
    unsigned long long ov = ((unsigned long long)__float_as_uint(acc1 * dv + bb.y) << 32)
                          |  (unsigned long long)__float_as_uint(acc0 * dv + bb.x);
    __builtin_nontemporal_store(ov, (unsigned long long*)(out + (size_t)v * C) + lane);
}

// ---------------------------------------------------------------- launcher (serial single stream — fork measured -10us, reverted)
extern "C" void kernel_launch(void* const* d_in, const int* in_sizes, int n_in,
                              void* d_out, int out_size, void* d_ws, size_t ws_size,
                              hipStream_t stream) {
    const float* X      = (const float*)d_in[0];
    const float* ew     = (const float*)d_in[1];
    const float* p      = (const float*)d_in[2];
    const float* W_ih   = (const float*)d_in[3];
    const float* W_hh   = (const float*)d_in[4];
    const float* b_ih   = (const float*)d_in[5];
    const float* b_hh   = (const float*)d_in[6];
    const float* W_conv = (const float*)d_in[7];
    const float* b_conv = (const float*)d_in[8];
    const int*   ei     = (const int*)d_in[9];
    const int N = in_sizes[0] / C;
    const int E = in_sizes[1];
    float* out = (float*)d_out;
    const int NBIN  = (N + 255) / 256;
    const int NBLKE = (E + 2047) / 2048;

    char* w = (char*)d_ws;
    auto alloc = [&](size_t bytes) -> void* {
        void* r = (void*)w;
        w += (bytes + 255) & ~(size_t)255;
        return r;
    };
    int*   hist   = (int*)alloc(HB * 4);
    size_t zbytes = (size_t)(w - (char*)d_ws);
    float* scores = (float*)alloc((size_t)N * 4);
    float* dinv   = (float*)alloc((size_t)N * 4);
    int*   offs   = (int*)alloc((size_t)(N + 1) * 4);
    int*   rh     = (int*)alloc((size_t)NBIN * NBLKE * 4);
    int*   tot    = (int*)alloc((size_t)NBIN * 4);
    int*   tidx   = (int*)alloc(C * 4);
    float* gate   = (float*)alloc(C * 4);
    float* wnewT  = (float*)alloc((size_t)C * C * 4);
    unsigned long long* sorted = (unsigned long long*)alloc((size_t)E * 8);
    unsigned* epack = (unsigned*)alloc((size_t)E * 4);
    unsigned* xwh = (unsigned*)alloc((size_t)N * 64 * 4);

    hipMemsetAsync(d_ws, 0, zbytes, stream);
    k_front<<<SHB + NBLKE, 1024, 0, stream>>>(X, p, scores, hist, ei, rh, N, E, NBIN, NBLKE);
    k_fsel<<<1, 1024, 0, stream>>>(scores, hist, p, tidx, gate, N);
    k_gru<<<C / 2, 256, 0, stream>>>(X, tidx, gate, W_conv, W_ih, W_hh, b_ih, b_hh, wnewT);
    k_rscanA<<<NBIN, 512, 0, stream>>>(rh, tot, NBLKE);
    k_rscat<<<NBLKE, 1024, 0, stream>>>(ei, ew, rh, tot, sorted, E, NBIN, NBLKE);
    k_bin<<<NBIN, 1024, 0, stream>>>(sorted, tot, offs, dinv, epack, N, E, NBIN);
    k_xw<<<(N + 127) / 128, 256, 0, stream>>>(X, wnewT, dinv, xwh, N);
    k_gather<<<(N + 3) / 4, 256, 0, stream>>>(xwh, offs, epack, dinv, b_conv, out, N);
}

// Round 4
// 218.441 us; speedup vs baseline: 1.0866x; 1.0866x over previous
//
#include <hip/hip_runtime.h>
#include <hip/hip_fp16.h>
#include <math.h>

#define C 128
#define HB 2048          // score histogram buckets (top 11 bits of ordered float)
#define NS 4096          // candidate capacity (pow2 for bitonic)
#define SHB 192          // score/hist blocks inside k_front

typedef __attribute__((ext_vector_type(8))) short bf16x8;
typedef __attribute__((ext_vector_type(4))) float f32x4;

__device__ inline unsigned ord_f32(float f) {
    unsigned u = __float_as_uint(f);
    return u ^ ((u & 0x80000000u) ? 0xFFFFFFFFu : 0x80000000u);
}
__device__ inline float unord_f32(unsigned u) {
    return __uint_as_float(u ^ ((u & 0x80000000u) ? 0x80000000u : 0xFFFFFFFFu));
}
__device__ inline short f2bf(float f) {        // RNE float -> bf16 bits
    unsigned u = __float_as_uint(f);
    return (short)((u + 0x7FFFu + ((u >> 16) & 1u)) >> 16);
}
__device__ inline float bf2f(short s) {
    return __uint_as_float(((unsigned)(unsigned short)s) << 16);
}

// ---------------------------------------------------------------- front: blocks [0,SHB) scores+hist; rest: MSD edge hist
__global__ __launch_bounds__(1024) void k_front(const float* __restrict__ X,
                                                const float* __restrict__ p,
                                                float* __restrict__ scores,
                                                int* __restrict__ hist,
                                                const int* __restrict__ ei,
                                                int* __restrict__ rh,
                                                int N, int E, int NBIN, int NBLKE) {
    int t = threadIdx.x;
    if (blockIdx.x < SHB) {
        __shared__ int lh[HB];
        for (int i = t; i < HB; i += 1024) lh[i] = 0;
        __syncthreads();
        int gw   = blockIdx.x * 16 + (t >> 6);     // SHB*16 waves total
        int lane = t & 63;
        const float2* p2 = (const float2*)p;
        float2 pv2 = p2[lane];
        for (int r = gw; r < N; r += SHB * 16) {
            const float2* xr = (const float2*)(X + (size_t)r * C);
            float2 x2 = xr[lane];
            float a = x2.x * pv2.x + x2.y * pv2.y;
            #pragma unroll
            for (int o = 32; o; o >>= 1) a += __shfl_down(a, o);
            if (lane == 0) {
                scores[r] = a;
                atomicAdd(&lh[ord_f32(a) >> 21], 1);
            }
        }
        __syncthreads();
        for (int i = t; i < HB; i += 1024) {
            int v = lh[i];
            if (v) atomicAdd(&hist[i], v);
        }
    } else {
        __shared__ int bh[8][256];                 // wave-pair private sub-histograms
        int cp = (t >> 7) & 7;
        for (int i = t; i < 8 * 256; i += 1024) ((int*)bh)[i] = 0;
        __syncthreads();
        int eb = blockIdx.x - SHB;
        int e = eb * 2048 + t * 2;
        if (e + 1 < E) {
            int2 d2 = *(const int2*)(ei + E + e);
            atomicAdd(&bh[cp][d2.x >> 8], 1);
            atomicAdd(&bh[cp][d2.y >> 8], 1);
        } else if (e < E) {
            atomicAdd(&bh[cp][ei[E + e] >> 8], 1);
        }
        __syncthreads();
        for (int i = t; i < NBIN; i += 1024) {
            int s = 0;
            #pragma unroll
            for (int c = 0; c < 8; c++) s += bh[c][i];
            rh[(size_t)i * NBLKE + eb] = s;
        }
    }
}

// ---------------------------------------------------------------- radix scan A: per-bin exclusive scan over blocks
__global__ __launch_bounds__(512) void k_rscanA(int* __restrict__ rh, int* __restrict__ tot, int NBLKE) {
    __shared__ int sc[512];
    int t = threadIdx.x;
    int bin = blockIdx.x;
    int v = (t < NBLKE) ? rh[(size_t)bin * NBLKE + t] : 0;
    sc[t] = v;
    __syncthreads();
    for (int off = 1; off < 512; off <<= 1) {
        int u = (t >= off) ? sc[t - off] : 0;
        __syncthreads();
        sc[t] += u;
        __syncthreads();
    }
    if (t < NBLKE) rh[(size_t)bin * NBLKE + t] = sc[t] - v;
    if (t == 511) tot[bin] = sc[511];
}

// ---------------------------------------------------------------- radix scatter: edges -> dst buckets (LDS cursors only)
__global__ __launch_bounds__(1024) void k_rscat(const int* __restrict__ ei, const float* __restrict__ ew,
                                                const int* __restrict__ rh, const int* __restrict__ tot,
                                                unsigned long long* __restrict__ sorted,
                                                int E, int NBIN, int NBLKE) {
    __shared__ int sc[256];
    __shared__ int cur[256];
    int t = threadIdx.x;
    int eb = blockIdx.x;
    int v = 0;
    if (t < 256) {
        v = (t < NBIN) ? tot[t] : 0;
        sc[t] = v;
    }
    __syncthreads();
    for (int off = 1; off < 256; off <<= 1) {
        int u = (t < 256 && t >= off) ? sc[t - off] : 0;
        __syncthreads();
        if (t < 256) sc[t] += u;
        __syncthreads();
    }
    if (t < NBIN) cur[t] = (sc[t] - v) + rh[(size_t)t * NBLKE + eb];
    __syncthreads();
    int e = eb * 2048 + t * 2;
    #pragma unroll
    for (int j = 0; j < 2; j++) {
        int ee = e + j;
        if (ee < E) {
            int s = ei[ee], d = ei[E + ee];
            float w = ew[ee];
            int pos = atomicAdd(&cur[d >> 8], 1);
            unsigned long long pk = ((unsigned long long)(unsigned)d << 48)
                                  | ((unsigned long long)(unsigned short)s << 32)
                                  |  (unsigned long long)__float_as_uint(w);
            sorted[pos] = pk;
        }
    }
}

// ---------------------------------------------------------------- per-bucket: counting sort by dst&255 + offs/deg/dinv
__global__ __launch_bounds__(1024) void k_bin(const unsigned long long* __restrict__ sorted,
                                              const int* __restrict__ tot,
                                              int* __restrict__ offs, float* __restrict__ dinv,
                                              unsigned* __restrict__ epack,
                                              int N, int E, int NBIN) {
    __shared__ int cnt[256];
    __shared__ float wsum[256];
    __shared__ int sc[256];
    __shared__ int cur2[256];
    __shared__ int s_base[2];
    int t = threadIdx.x;
    int b = blockIdx.x;
    // recompute bin base from tot
    int v = 0;
    if (t < 256) {
        v = (t < NBIN) ? tot[t] : 0;
        sc[t] = v;
    }
    __syncthreads();
    for (int off = 1; off < 256; off <<= 1) {
        int u = (t < 256 && t >= off) ? sc[t - off] : 0;
        __syncthreads();
        if (t < 256) sc[t] += u;
        __syncthreads();
    }
    if (t == b) { s_base[0] = sc[t] - v; s_base[1] = sc[t]; }
    __syncthreads();
    int s0 = s_base[0], s1 = s_base[1];
    for (int i = t; i < 256; i += 1024) { cnt[i] = 0; wsum[i] = 0.f; }
    __syncthreads();
    for (int i = s0 + t; i < s1; i += 1024) {
        unsigned long long pk = sorted[i];
        int d8 = (int)(pk >> 48) & 255;
        float w = __uint_as_float((unsigned)(pk & 0xFFFFFFFFull));
        atomicAdd(&cnt[d8], 1);
        atomicAdd(&wsum[d8], w);
    }
    __syncthreads();
    int cv = (t < 256) ? cnt[t] : 0;
    if (t < 256) sc[t] = cv;
    __syncthreads();
    for (int off = 1; off < 256; off <<= 1) {
        int u = (t < 256 && t >= off) ? sc[t - off] : 0;
        __syncthreads();
        if (t < 256) sc[t] += u;
        __syncthreads();
    }
    if (t < 256) {
        int loff = sc[t] - cv;
        cur2[t] = s0 + loff;
        int node = b * 256 + t;
        if (node < N) {
            offs[node] = s0 + loff;
            dinv[node] = rsqrtf(1.0f + wsum[t]);
        }
    }
    if (b == NBIN - 1 && t == 0) offs[N] = E;
    __syncthreads();
    for (int i = s0 + t; i < s1; i += 1024) {
        unsigned long long pk = sorted[i];
        int d8 = (int)(pk >> 48) & 255;
        unsigned src = (unsigned)((pk >> 32) & 0xFFFFu);
        float w = __uint_as_float((unsigned)(pk & 0xFFFFFFFFull));
        int pos = atomicAdd(&cur2[d8], 1);
        __half hw = __float2half(w);
        epack[pos] = ((unsigned)*(unsigned short*)&hw << 16) | src;
    }
}

// ---------------------------------------------------------------- filter with inline threshold scan
__global__ __launch_bounds__(256) void k_filter(const float* __restrict__ scores,
                                                const int* __restrict__ hist,
                                                int* __restrict__ nc,
                                                unsigned long long* __restrict__ cand, int N) {
    __shared__ int sc[256];
    __shared__ int sT;
    int t = threadIdx.x;
    int loc[8];
    int sum = 0;
    #pragma unroll
    for (int s = 0; s < 8; s++) {
        loc[s] = hist[HB - 1 - (t * 8 + s)];
        sum += loc[s];
    }
    sc[t] = sum;
    __syncthreads();
    for (int off = 1; off < 256; off <<= 1) {
        int v = (t >= off) ? sc[t - off] : 0;
        __syncthreads();
        sc[t] += v;
        __syncthreads();
    }
    int run = sc[t] - sum;
    #pragma unroll
    for (int s = 0; s < 8; s++) {
        int b = HB - 1 - (t * 8 + s);
        int nr = run + loc[s];
        if (run < C && nr >= C) sT = b;
        run = nr;
    }
    __syncthreads();
    int T = sT;
    int i = blockIdx.x * 256 + t;
    if (i < N) {
        unsigned u = ord_f32(scores[i]);
        if ((int)(u >> 21) >= T) {
            int pos = atomicAdd(nc, 1);
            if (pos < NS)
                cand[pos] = ((unsigned long long)u << 32) | (unsigned)(~(unsigned)i);
        }
    }
}

// ---------------------------------------------------------------- adaptive bitonic sort desc, emit top-128
__global__ __launch_bounds__(1024) void k_sel(const unsigned long long* __restrict__ cand,
                                              const int* __restrict__ nc,
                                              const float* __restrict__ p,
                                              int* __restrict__ tidx, float* __restrict__ gate) {
    __shared__ unsigned long long sk[NS];
    __shared__ float red[16];
    __shared__ float s_pn;
    int t = threadIdx.x;
    int M = *nc; if (M > NS) M = NS;
    int S = 256; while (S < M) S <<= 1;
    for (int i = t; i < S; i += 1024) sk[i] = (i < M) ? cand[i] : 0ULL;
    float pv = 0.f;
    if (t < C) { float x = p[t]; pv = x * x; }
    #pragma unroll
    for (int o = 32; o; o >>= 1) pv += __shfl_down(pv, o);
    if ((t & 63) == 0) red[t >> 6] = pv;
    __syncthreads();
    if (t == 0) {
        float s = 0.f;
        for (int i = 0; i < 16; i++) s += red[i];
        s_pn = sqrtf(s);
    }
    for (int k = 2; k <= S; k <<= 1) {
        for (int j = k >> 1; j > 0; j >>= 1) {
            __syncthreads();
            for (int idx = t; idx < S; idx += 1024) {
                int l = idx ^ j;
                if (l > idx) {
                    unsigned long long a = sk[idx], b = sk[l];
                    bool desc = (idx & k) == 0;
                    if (desc ? (a < b) : (a > b)) { sk[idx] = b; sk[l] = a; }
                }
            }
        }
    }
    __syncthreads();
    if (t < C) {
        unsigned long long g = sk[t];
        tidx[t] = (int)(~(unsigned)(g & 0xFFFFFFFFull));
        gate[t] = tanhf(unord_f32((unsigned)(g >> 32)) / s_pn);
    }
}

// ---------------------------------------------------------------- GRU step (X_tilde folded in) -> W_new^T
__global__ __launch_bounds__(256) void k_gru(const float* __restrict__ X,
                                             const int* __restrict__ tidx,
                                             const float* __restrict__ gate,
                                             const float* __restrict__ Wc,
                                             const float* __restrict__ W_ih, const float* __restrict__ W_hh,
                                             const float* __restrict__ b_ih, const float* __restrict__ b_hh,
                                             float* __restrict__ wnewT) {
    int t = threadIdx.x;
    int i = t & 127;
    int j = blockIdx.x * 2 + (t >> 7);
    int src = tidx[i];
    float g = gate[i];
    const float4* xr   = (const float4*)(X + (size_t)src * C);
    const float4* hr   = (const float4*)(Wc + (size_t)i * C);
    const float4* wri  = (const float4*)(W_ih + (size_t)j * C);
    const float4* wzi  = (const float4*)(W_ih + (size_t)(C + j) * C);
    const float4* wni  = (const float4*)(W_ih + (size_t)(2 * C + j) * C);
    const float4* wrh  = (const float4*)(W_hh + (size_t)j * C);
    const float4* wzh  = (const float4*)(W_hh + (size_t)(C + j) * C);
    const float4* wnh  = (const float4*)(W_hh + (size_t)(2 * C + j) * C);
    float gir = 0, giz = 0, gin = 0, ghr = 0, ghz = 0, ghn = 0;
    #pragma unroll 8
    for (int k4 = 0; k4 < C / 4; k4++) {
        float4 x = xr[k4], h = hr[k4], a;
        a = wri[k4]; gir += x.x * a.x + x.y * a.y + x.z * a.z + x.w * a.w;
        a = wzi[k4]; giz += x.x * a.x + x.y * a.y + x.z * a.z + x.w * a.w;
        a = wni[k4]; gin += x.x * a.x + x.y * a.y + x.z * a.z + x.w * a.w;
        a = wrh[k4]; ghr += h.x * a.x + h.y * a.y + h.z * a.z + h.w * a.w;
        a = wzh[k4]; ghz += h.x * a.x + h.y * a.y + h.z * a.z + h.w * a.w;
        a = wnh[k4]; ghn += h.x * a.x + h.y * a.y + h.z * a.z + h.w * a.w;
    }
    gir = g * gir + b_ih[j];         ghr += b_hh[j];
    giz = g * giz + b_ih[C + j];     ghz += b_hh[C + j];
    gin = g * gin + b_ih[2 * C + j]; ghn += b_hh[2 * C + j];
    float r = 1.f / (1.f + expf(-(gir + ghr)));
    float z = 1.f / (1.f + expf(-(giz + ghz)));
    float n = tanhf(gin + r * ghn);
    float wn = (1.f - z) * n + z * Wc[(size_t)i * C + j];
    wnewT[(size_t)j * C + i] = wn;
}

// ---------------------------------------------------------------- Xw rows = dinv[r]*(X @ W_new^T)[r], stored fp16
__global__ __launch_bounds__(256) void k_xw(const float* __restrict__ X,
                                            const float* __restrict__ wnewT,
                                            const float* __restrict__ dinv,
                                            unsigned* __restrict__ xwh, int N) {
    __shared__ short Bh[C * C];
    __shared__ short Bl[C * C];
    int t = threadIdx.x;
    for (int idx = t; idx < C * C; idx += 256) {
        int k = idx >> 7, c = idx & 127;
        float wv = wnewT[idx];
        short hi = f2bf(wv);
        float lo = wv - bf2f(hi);
        int pos = c * C + (k ^ ((c & 15) << 3));
        Bh[pos] = hi;
        Bl[pos] = f2bf(lo);
    }
    __syncthreads();

    int wave = t >> 6, lane = t & 63;
    int ln = lane & 15, quad = lane >> 4;
    int r0 = blockIdx.x * 128 + wave * 32;

    f32x4 acc[2][8];
    #pragma unroll
    for (int mt = 0; mt < 2; mt++)
        #pragma unroll
        for (int ct = 0; ct < 8; ct++) { acc[mt][ct][0] = 0.f; acc[mt][ct][1] = 0.f; acc[mt][ct][2] = 0.f; acc[mt][ct][3] = 0.f; }

    int row0 = r0 + ln;       if (row0 >= N) row0 = N - 1;
    int row1 = r0 + 16 + ln;  if (row1 >= N) row1 = N - 1;
    const float* xr0 = X + (size_t)row0 * C + quad * 8;
    const float* xr1 = X + (size_t)row1 * C + quad * 8;

    for (int ks = 0; ks < 4; ks++) {
        float a0[8], a1[8];
        *(float4*)&a0[0] = *(const float4*)(xr0 + ks * 32);
        *(float4*)&a0[4] = *(const float4*)(xr0 + ks * 32 + 4);
        *(float4*)&a1[0] = *(const float4*)(xr1 + ks * 32);
        *(float4*)&a1[4] = *(const float4*)(xr1 + ks * 32 + 4);
        bf16x8 a0h, a0l, a1h, a1l;
        #pragma unroll
        for (int j = 0; j < 8; j++) {
            short h0 = f2bf(a0[j]); a0h[j] = h0; a0l[j] = f2bf(a0[j] - bf2f(h0));
            short h1 = f2bf(a1[j]); a1h[j] = h1; a1l[j] = f2bf(a1[j] - bf2f(h1));
        }
        int kb = ks * 32 + quad * 8;
        int koff = kb ^ (ln << 3);
        #pragma unroll
        for (int ct = 0; ct < 8; ct++) {
            int pos = (ct * 16 + ln) * C + koff;
            bf16x8 bh = *(bf16x8*)&Bh[pos];
            bf16x8 bl = *(bf16x8*)&Bl[pos];
            acc[0][ct] = __builtin_amdgcn_mfma_f32_16x16x32_bf16(a0h, bh, acc[0][ct], 0, 0, 0);
            acc[0][ct] = __builtin_amdgcn_mfma_f32_16x16x32_bf16(a0l, bh, acc[0][ct], 0, 0, 0);
            acc[0][ct] = __builtin_amdgcn_mfma_f32_16x16x32_bf16(a0h, bl, acc[0][ct], 0, 0, 0);
            acc[1][ct] = __builtin_amdgcn_mfma_f32_16x16x32_bf16(a1h, bh, acc[1][ct], 0, 0, 0);
            acc[1][ct] = __builtin_amdgcn_mfma_f32_16x16x32_bf16(a1l, bh, acc[1][ct], 0, 0, 0);
            acc[1][ct] = __builtin_amdgcn_mfma_f32_16x16x32_bf16(a1h, bl, acc[1][ct], 0, 0, 0);
        }
    }

    // D layout (m89): col = lane&15, row = quad*4 + reg; store half(dinv[r]*val)
    __half* H = (__half*)xwh;
    #pragma unroll
    for (int mt = 0; mt < 2; mt++) {
        int rbase = r0 + mt * 16 + quad * 4;
        #pragma unroll
        for (int reg = 0; reg < 4; reg++) {
            int r = rbase + reg;
            if (r < N) {
                float dvr = dinv[r];
                #pragma unroll
                for (int ct = 0; ct < 8; ct++) {
                    int col = ct * 16 + ln;
                    H[(size_t)r * C + col] = __float2half(acc[mt][ct][reg] * dvr);
                }
            }
        }
    }
}

// ---------------------------------------------------------------- gather v2: wave/node, half-wave per edge (2 edges/VMEM op)
// epack loaded 64-wide once per chunk then broadcast via __shfl (DS pipe, not VMEM).
// Lanes >= m load pkl=0 -> weight +0.0, src 0 -> contributes exactly 0 (no branches).
__global__ __launch_bounds__(256) void k_gather(const unsigned* __restrict__ xwh,
                                                const int* __restrict__ offs,
                                                const unsigned* __restrict__ epack,
                                                const float* __restrict__ dinv,
                                                const float* __restrict__ b_conv,
                                                float* __restrict__ out, int N) {
    int t = threadIdx.x;
    int v = blockIdx.x * 4 + (t >> 6);
    int lane = t & 63;
    if (v >= N) return;
    int h = lane >> 5;              // half-wave: 0 = even edges, 1 = odd edges
    int q = lane & 31;              // covers cols 4q .. 4q+3
    float dv = dinv[v];

    float ax = 0.f, ay = 0.f, az = 0.f, aw = 0.f;
    if (h == 0) {                   // self-loop only on half 0 (combined later)
        uint2 sv = *(const uint2*)(xwh + (size_t)v * 64 + q * 2);
        __half2 s0 = *(__half2*)&sv.x, s1 = *(__half2*)&sv.y;
        ax = __low2float(s0); ay = __high2float(s0);
        az = __low2float(s1); aw = __high2float(s1);
    }

    int e0 = offs[v], e1 = offs[v + 1];
    for (int base = e0; base < e1; base += 64) {
        int m = e1 - base; if (m > 64) m = 64;
        unsigned pkl = (lane < m) ? __builtin_nontemporal_load(&epack[base + lane]) : 0u;
        int pairs = (m + 1) >> 1;
        int jj = 0;
        for (; jj + 3 < pairs; jj += 4) {
            unsigned pa[4]; uint2 rx[4];
            #pragma unroll
            for (int u = 0; u < 4; u++) pa[u] = __shfl(pkl, 2 * (jj + u) + h);
            #pragma unroll
            for (int u = 0; u < 4; u++)
                rx[u] = *(const uint2*)(xwh + (size_t)(pa[u] & 0xFFFFu) * 64 + q * 2);
            #pragma unroll
            for (int u = 0; u < 4; u++) {
                unsigned short hs = (unsigned short)(pa[u] >> 16);
                float nm = __half2float(*(__half*)&hs);
                __half2 r0 = *(__half2*)&rx[u].x;
                __half2 r1 = *(__half2*)&rx[u].y;
                ax += nm * __low2float(r0);  ay += nm * __high2float(r0);
                az += nm * __low2float(r1);  aw += nm * __high2float(r1);
            }
        }
        for (; jj < pairs; jj++) {
            unsigned pa = __shfl(pkl, 2 * jj + h);
            uint2 rx = *(const uint2*)(xwh + (size_t)(pa & 0xFFFFu) * 64 + q * 2);
            unsigned short hs = (unsigned short)(pa >> 16);
            float nm = __half2float(*(__half*)&hs);
            __half2 r0 = *(__half2*)&rx.x;
            __half2 r1 = *(__half2*)&rx.y;
            ax += nm * __low2float(r0);  ay += nm * __high2float(r0);
            az += nm * __low2float(r1);  aw += nm * __high2float(r1);
        }
    }

    // combine odd-edge half into even-edge half
    ax += __shfl_xor(ax, 32);
    ay += __shfl_xor(ay, 32);
    az += __shfl_xor(az, 32);
    aw += __shfl_xor(aw, 32);

    if (h == 0) {
        const float* bbp = b_conv + q * 4;
        f32x4 o;
        o[0] = ax * dv + bbp[0];
        o[1] = ay * dv + bbp[1];
        o[2] = az * dv + bbp[2];
        o[3] = aw * dv + bbp[3];
        __builtin_nontemporal_store(o, (f32x4*)(out + (size_t)v * C + q * 4));
    }
}

// ---------------------------------------------------------------- launcher (R0 structure: serial, 9 dispatches)
extern "C" void kernel_launch(void* const* d_in, const int* in_sizes, int n_in,
                              void* d_out, int out_size, void* d_ws, size_t ws_size,
                              hipStream_t stream) {
    const float* X      = (const float*)d_in[0];
    const float* ew     = (const float*)d_in[1];
    const float* p      = (const float*)d_in[2];
    const float* W_ih   = (const float*)d_in[3];
    const float* W_hh   = (const float*)d_in[4];
    const float* b_ih   = (const float*)d_in[5];
    const float* b_hh   = (const float*)d_in[6];
    const float* W_conv = (const float*)d_in[7];
    const float* b_conv = (const float*)d_in[8];
    const int*   ei     = (const int*)d_in[9];
    const int N = in_sizes[0] / C;
    const int E = in_sizes[1];
    float* out = (float*)d_out;
    const int NB    = (N + 255) / 256;
    const int NBIN  = (N + 255) / 256;
    const int NBLKE = (E + 2047) / 2048;

    char* w = (char*)d_ws;
    auto alloc = [&](size_t bytes) -> void* {
        void* r = (void*)w;
        w += (bytes + 255) & ~(size_t)255;
        return r;
    };
    int*   hist   = (int*)alloc(HB * 4);
    int*   nc     = (int*)alloc(256);
    size_t zbytes = (size_t)(w - (char*)d_ws);
    float* scores = (float*)alloc((size_t)N * 4);
    float* dinv   = (float*)alloc((size_t)N * 4);
    int*   offs   = (int*)alloc((size_t)(N + 1) * 4);
    int*   rh     = (int*)alloc((size_t)NBIN * NBLKE * 4);
    int*   tot    = (int*)alloc((size_t)NBIN * 4);
    unsigned long long* cand = (unsigned long long*)alloc((size_t)NS * 8);
    int*   tidx   = (int*)alloc(C * 4);
    float* gate   = (float*)alloc(C * 4);
    float* wnewT  = (float*)alloc((size_t)C * C * 4);
    unsigned long long* sorted = (unsigned long long*)alloc((size_t)E * 8);
    unsigned* epack = (unsigned*)alloc((size_t)E * 4);
    unsigned* xwh = (unsigned*)alloc((size_t)N * 64 * 4);

    hipMemsetAsync(d_ws, 0, zbytes, stream);
    k_front<<<SHB + NBLKE, 1024, 0, stream>>>(X, p, scores, hist, ei, rh, N, E, NBIN, NBLKE);
    k_filter<<<NB, 256, 0, stream>>>(scores, hist, nc, cand, N);
    k_sel<<<1, 1024, 0, stream>>>(cand, nc, p, tidx, gate);
    k_gru<<<C / 2, 256, 0, stream>>>(X, tidx, gate, W_conv, W_ih, W_hh, b_ih, b_hh, wnewT);
    k_rscanA<<<NBIN, 512, 0, stream>>>(rh, tot, NBLKE);
    k_rscat<<<NBLKE, 1024, 0, stream>>>(ei, ew, rh, tot, sorted, E, NBIN, NBLKE);
    k_bin<<<NBIN, 1024, 0, stream>>>(sorted, tot, offs, dinv, epack, N, E, NBIN);
    k_xw<<<(N + 127) / 128, 256, 0, stream>>>(X, wnewT, dinv, xwh, N);
    k_gather<<<(N + 3) / 4, 256, 0, stream>>>(xwh, offs, epack, dinv, b_conv, out, N);
}

// Round 5
// 218.181 us; speedup vs baseline: 1.0879x; 1.0012x over previous
//
#include <hip/hip_runtime.h>
#include <hip/hip_fp16.h>
#include <math.h>

#define C 128
#define HB 2048          // score histogram buckets (top 11 bits of ordered float)
#define NS 4096          // candidate capacity (pow2 for bitonic)
#define SHB 192          // score/hist blocks inside k_front

typedef __attribute__((ext_vector_type(8))) short bf16x8;
typedef __attribute__((ext_vector_type(4))) float f32x4;

__device__ inline unsigned ord_f32(float f) {
    unsigned u = __float_as_uint(f);
    return u ^ ((u & 0x80000000u) ? 0xFFFFFFFFu : 0x80000000u);
}
__device__ inline float unord_f32(unsigned u) {
    return __uint_as_float(u ^ ((u & 0x80000000u) ? 0x80000000u : 0xFFFFFFFFu));
}
__device__ inline short f2bf(float f) {        // RNE float -> bf16 bits
    unsigned u = __float_as_uint(f);
    return (short)((u + 0x7FFFu + ((u >> 16) & 1u)) >> 16);
}
__device__ inline float bf2f(short s) {
    return __uint_as_float(((unsigned)(unsigned short)s) << 16);
}

// ---------------------------------------------------------------- front: blocks [0,SHB) scores+hist; rest: MSD edge hist
__global__ __launch_bounds__(1024) void k_front(const float* __restrict__ X,
                                                const float* __restrict__ p,
                                                float* __restrict__ scores,
                                                int* __restrict__ hist,
                                                const int* __restrict__ ei,
                                                int* __restrict__ rh,
                                                int N, int E, int NBIN, int NBLKE) {
    int t = threadIdx.x;
    if (blockIdx.x < SHB) {
        __shared__ int lh[HB];
        for (int i = t; i < HB; i += 1024) lh[i] = 0;
        __syncthreads();
        int gw   = blockIdx.x * 16 + (t >> 6);     // SHB*16 waves total
        int lane = t & 63;
        const float2* p2 = (const float2*)p;
        float2 pv2 = p2[lane];
        for (int r = gw; r < N; r += SHB * 16) {
            const float2* xr = (const float2*)(X + (size_t)r * C);
            float2 x2 = xr[lane];
            float a = x2.x * pv2.x + x2.y * pv2.y;
            #pragma unroll
            for (int o = 32; o; o >>= 1) a += __shfl_down(a, o);
            if (lane == 0) {
                scores[r] = a;
                atomicAdd(&lh[ord_f32(a) >> 21], 1);
            }
        }
        __syncthreads();
        for (int i = t; i < HB; i += 1024) {
            int v = lh[i];
            if (v) atomicAdd(&hist[i], v);
        }
    } else {
        __shared__ int bh[8][256];                 // wave-pair private sub-histograms
        int cp = (t >> 7) & 7;
        for (int i = t; i < 8 * 256; i += 1024) ((int*)bh)[i] = 0;
        __syncthreads();
        int eb = blockIdx.x - SHB;
        int e = eb * 2048 + t * 2;
        if (e + 1 < E) {
            int2 d2 = *(const int2*)(ei + E + e);
            atomicAdd(&bh[cp][d2.x >> 8], 1);
            atomicAdd(&bh[cp][d2.y >> 8], 1);
        } else if (e < E) {
            atomicAdd(&bh[cp][ei[E + e] >> 8], 1);
        }
        __syncthreads();
        for (int i = t; i < NBIN; i += 1024) {
            int s = 0;
            #pragma unroll
            for (int c = 0; c < 8; c++) s += bh[c][i];
            rh[(size_t)i * NBLKE + eb] = s;
        }
    }
}

// ---------------------------------------------------------------- radix scan A: per-bin exclusive scan over blocks
__global__ __launch_bounds__(512) void k_rscanA(int* __restrict__ rh, int* __restrict__ tot, int NBLKE) {
    __shared__ int sc[512];
    int t = threadIdx.x;
    int bin = blockIdx.x;
    int v = (t < NBLKE) ? rh[(size_t)bin * NBLKE + t] : 0;
    sc[t] = v;
    __syncthreads();
    for (int off = 1; off < 512; off <<= 1) {
        int u = (t >= off) ? sc[t - off] : 0;
        __syncthreads();
        sc[t] += u;
        __syncthreads();
    }
    if (t < NBLKE) rh[(size_t)bin * NBLKE + t] = sc[t] - v;
    if (t == 511) tot[bin] = sc[511];
}

// ---------------------------------------------------------------- radix scatter: edges -> dst buckets (LDS cursors only)
__global__ __launch_bounds__(1024) void k_rscat(const int* __restrict__ ei, const float* __restrict__ ew,
                                                const int* __restrict__ rh, const int* __restrict__ tot,
                                                unsigned long long* __restrict__ sorted,
                                                int E, int NBIN, int NBLKE) {
    __shared__ int sc[256];
    __shared__ int cur[256];
    int t = threadIdx.x;
    int eb = blockIdx.x;
    int v = 0;
    if (t < 256) {
        v = (t < NBIN) ? tot[t] : 0;
        sc[t] = v;
    }
    __syncthreads();
    for (int off = 1; off < 256; off <<= 1) {
        int u = (t < 256 && t >= off) ? sc[t - off] : 0;
        __syncthreads();
        if (t < 256) sc[t] += u;
        __syncthreads();
    }
    if (t < NBIN) cur[t] = (sc[t] - v) + rh[(size_t)t * NBLKE + eb];
    __syncthreads();
    int e = eb * 2048 + t * 2;
    #pragma unroll
    for (int j = 0; j < 2; j++) {
        int ee = e + j;
        if (ee < E) {
            int s = ei[ee], d = ei[E + ee];
            float w = ew[ee];
            int pos = atomicAdd(&cur[d >> 8], 1);
            unsigned long long pk = ((unsigned long long)(unsigned)d << 48)
                                  | ((unsigned long long)(unsigned short)s << 32)
                                  |  (unsigned long long)__float_as_uint(w);
            sorted[pos] = pk;
        }
    }
}

// ---------------------------------------------------------------- per-bucket: counting sort by dst&255 + offs/deg/dinv
__global__ __launch_bounds__(1024) void k_bin(const unsigned long long* __restrict__ sorted,
                                              const int* __restrict__ tot,
                                              int* __restrict__ offs, float* __restrict__ dinv,
                                              unsigned* __restrict__ epack,
                                              int N, int E, int NBIN) {
    __shared__ int cnt[256];
    __shared__ float wsum[256];
    __shared__ int sc[256];
    __shared__ int cur2[256];
    __shared__ int s_base[2];
    int t = threadIdx.x;
    int b = blockIdx.x;
    // recompute bin base from tot
    int v = 0;
    if (t < 256) {
        v = (t < NBIN) ? tot[t] : 0;
        sc[t] = v;
    }
    __syncthreads();
    for (int off = 1; off < 256; off <<= 1) {
        int u = (t < 256 && t >= off) ? sc[t - off] : 0;
        __syncthreads();
        if (t < 256) sc[t] += u;
        __syncthreads();
    }
    if (t == b) { s_base[0] = sc[t] - v; s_base[1] = sc[t]; }
    __syncthreads();
    int s0 = s_base[0], s1 = s_base[1];
    for (int i = t; i < 256; i += 1024) { cnt[i] = 0; wsum[i] = 0.f; }
    __syncthreads();
    for (int i = s0 + t; i < s1; i += 1024) {
        unsigned long long pk = sorted[i];
        int d8 = (int)(pk >> 48) & 255;
        float w = __uint_as_float((unsigned)(pk & 0xFFFFFFFFull));
        atomicAdd(&cnt[d8], 1);
        atomicAdd(&wsum[d8], w);
    }
    __syncthreads();
    int cv = (t < 256) ? cnt[t] : 0;
    if (t < 256) sc[t] = cv;
    __syncthreads();
    for (int off = 1; off < 256; off <<= 1) {
        int u = (t < 256 && t >= off) ? sc[t - off] : 0;
        __syncthreads();
        if (t < 256) sc[t] += u;
        __syncthreads();
    }
    if (t < 256) {
        int loff = sc[t] - cv;
        cur2[t] = s0 + loff;
        int node = b * 256 + t;
        if (node < N) {
            offs[node] = s0 + loff;
            dinv[node] = rsqrtf(1.0f + wsum[t]);
        }
    }
    if (b == NBIN - 1 && t == 0) offs[N] = E;
    __syncthreads();
    for (int i = s0 + t; i < s1; i += 1024) {
        unsigned long long pk = sorted[i];
        int d8 = (int)(pk >> 48) & 255;
        unsigned src = (unsigned)((pk >> 32) & 0xFFFFu);
        float w = __uint_as_float((unsigned)(pk & 0xFFFFFFFFull));
        int pos = atomicAdd(&cur2[d8], 1);
        __half hw = __float2half(w);
        epack[pos] = ((unsigned)*(unsigned short*)&hw << 16) | src;
    }
}

// ---------------------------------------------------------------- filter with inline threshold scan
__global__ __launch_bounds__(256) void k_filter(const float* __restrict__ scores,
                                                const int* __restrict__ hist,
                                                int* __restrict__ nc,
                                                unsigned long long* __restrict__ cand, int N) {
    __shared__ int sc[256];
    __shared__ int sT;
    int t = threadIdx.x;
    int loc[8];
    int sum = 0;
    #pragma unroll
    for (int s = 0; s < 8; s++) {
        loc[s] = hist[HB - 1 - (t * 8 + s)];
        sum += loc[s];
    }
    sc[t] = sum;
    __syncthreads();
    for (int off = 1; off < 256; off <<= 1) {
        int v = (t >= off) ? sc[t - off] : 0;
        __syncthreads();
        sc[t] += v;
        __syncthreads();
    }
    int run = sc[t] - sum;
    #pragma unroll
    for (int s = 0; s < 8; s++) {
        int b = HB - 1 - (t * 8 + s);
        int nr = run + loc[s];
        if (run < C && nr >= C) sT = b;
        run = nr;
    }
    __syncthreads();
    int T = sT;
    int i = blockIdx.x * 256 + t;
    if (i < N) {
        unsigned u = ord_f32(scores[i]);
        if ((int)(u >> 21) >= T) {
            int pos = atomicAdd(nc, 1);
            if (pos < NS)
                cand[pos] = ((unsigned long long)u << 32) | (unsigned)(~(unsigned)i);
        }
    }
}

// ---------------------------------------------------------------- adaptive bitonic sort desc, emit top-128
__global__ __launch_bounds__(1024) void k_sel(const unsigned long long* __restrict__ cand,
                                              const int* __restrict__ nc,
                                              const float* __restrict__ p,
                                              int* __restrict__ tidx, float* __restrict__ gate) {
    __shared__ unsigned long long sk[NS];
    __shared__ float red[16];
    __shared__ float s_pn;
    int t = threadIdx.x;
    int M = *nc; if (M > NS) M = NS;
    int S = 256; while (S < M) S <<= 1;
    for (int i = t; i < S; i += 1024) sk[i] = (i < M) ? cand[i] : 0ULL;
    float pv = 0.f;
    if (t < C) { float x = p[t]; pv = x * x; }
    #pragma unroll
    for (int o = 32; o; o >>= 1) pv += __shfl_down(pv, o);
    if ((t & 63) == 0) red[t >> 6] = pv;
    __syncthreads();
    if (t == 0) {
        float s = 0.f;
        for (int i = 0; i < 16; i++) s += red[i];
        s_pn = sqrtf(s);
    }
    for (int k = 2; k <= S; k <<= 1) {
        for (int j = k >> 1; j > 0; j >>= 1) {
            __syncthreads();
            for (int idx = t; idx < S; idx += 1024) {
                int l = idx ^ j;
                if (l > idx) {
                    unsigned long long a = sk[idx], b = sk[l];
                    bool desc = (idx & k) == 0;
                    if (desc ? (a < b) : (a > b)) { sk[idx] = b; sk[l] = a; }
                }
            }
        }
    }
    __syncthreads();
    if (t < C) {
        unsigned long long g = sk[t];
        tidx[t] = (int)(~(unsigned)(g & 0xFFFFFFFFull));
        gate[t] = tanhf(unord_f32((unsigned)(g >> 32)) / s_pn);
    }
}

// ---------------------------------------------------------------- GRU step (X_tilde folded in) -> W_new^T
__global__ __launch_bounds__(256) void k_gru(const float* __restrict__ X,
                                             const int* __restrict__ tidx,
                                             const float* __restrict__ gate,
                                             const float* __restrict__ Wc,
                                             const float* __restrict__ W_ih, const float* __restrict__ W_hh,
                                             const float* __restrict__ b_ih, const float* __restrict__ b_hh,
                                             float* __restrict__ wnewT) {
    int t = threadIdx.x;
    int i = t & 127;
    int j = blockIdx.x * 2 + (t >> 7);
    int src = tidx[i];
    float g = gate[i];
    const float4* xr   = (const float4*)(X + (size_t)src * C);
    const float4* hr   = (const float4*)(Wc + (size_t)i * C);
    const float4* wri  = (const float4*)(W_ih + (size_t)j * C);
    const float4* wzi  = (const float4*)(W_ih + (size_t)(C + j) * C);
    const float4* wni  = (const float4*)(W_ih + (size_t)(2 * C + j) * C);
    const float4* wrh  = (const float4*)(W_hh + (size_t)j * C);
    const float4* wzh  = (const float4*)(W_hh + (size_t)(C + j) * C);
    const float4* wnh  = (const float4*)(W_hh + (size_t)(2 * C + j) * C);
    float gir = 0, giz = 0, gin = 0, ghr = 0, ghz = 0, ghn = 0;
    #pragma unroll 8
    for (int k4 = 0; k4 < C / 4; k4++) {
        float4 x = xr[k4], h = hr[k4], a;
        a = wri[k4]; gir += x.x * a.x + x.y * a.y + x.z * a.z + x.w * a.w;
        a = wzi[k4]; giz += x.x * a.x + x.y * a.y + x.z * a.z + x.w * a.w;
        a = wni[k4]; gin += x.x * a.x + x.y * a.y + x.z * a.z + x.w * a.w;
        a = wrh[k4]; ghr += h.x * a.x + h.y * a.y + h.z * a.z + h.w * a.w;
        a = wzh[k4]; ghz += h.x * a.x + h.y * a.y + h.z * a.z + h.w * a.w;
        a = wnh[k4]; ghn += h.x * a.x + h.y * a.y + h.z * a.z + h.w * a.w;
    }
    gir = g * gir + b_ih[j];         ghr += b_hh[j];
    giz = g * giz + b_ih[C + j];     ghz += b_hh[C + j];
    gin = g * gin + b_ih[2 * C + j]; ghn += b_hh[2 * C + j];
    float r = 1.f / (1.f + expf(-(gir + ghr)));
    float z = 1.f / (1.f + expf(-(giz + ghz)));
    float n = tanhf(gin + r * ghn);
    float wn = (1.f - z) * n + z * Wc[(size_t)i * C + j];
    wnewT[(size_t)j * C + i] = wn;
}

// ---------------------------------------------------------------- Xw rows = dinv[r]*(X @ W_new^T)[r], stored fp16
__global__ __launch_bounds__(256) void k_xw(const float* __restrict__ X,
                                            const float* __restrict__ wnewT,
                                            const float* __restrict__ dinv,
                                            unsigned* __restrict__ xwh, int N) {
    __shared__ short Bh[C * C];
    __shared__ short Bl[C * C];
    int t = threadIdx.x;
    for (int idx = t; idx < C * C; idx += 256) {
        int k = idx >> 7, c = idx & 127;
        float wv = wnewT[idx];
        short hi = f2bf(wv);
        float lo = wv - bf2f(hi);
        int pos = c * C + (k ^ ((c & 15) << 3));
        Bh[pos] = hi;
        Bl[pos] = f2bf(lo);
    }
    __syncthreads();

    int wave = t >> 6, lane = t & 63;
    int ln = lane & 15, quad = lane >> 4;
    int r0 = blockIdx.x * 128 + wave * 32;

    f32x4 acc[2][8];
    #pragma unroll
    for (int mt = 0; mt < 2; mt++)
        #pragma unroll
        for (int ct = 0; ct < 8; ct++) { acc[mt][ct][0] = 0.f; acc[mt][ct][1] = 0.f; acc[mt][ct][2] = 0.f; acc[mt][ct][3] = 0.f; }

    int row0 = r0 + ln;       if (row0 >= N) row0 = N - 1;
    int row1 = r0 + 16 + ln;  if (row1 >= N) row1 = N - 1;
    const float* xr0 = X + (size_t)row0 * C + quad * 8;
    const float* xr1 = X + (size_t)row1 * C + quad * 8;

    for (int ks = 0; ks < 4; ks++) {
        float a0[8], a1[8];
        *(float4*)&a0[0] = *(const float4*)(xr0 + ks * 32);
        *(float4*)&a0[4] = *(const float4*)(xr0 + ks * 32 + 4);
        *(float4*)&a1[0] = *(const float4*)(xr1 + ks * 32);
        *(float4*)&a1[4] = *(const float4*)(xr1 + ks * 32 + 4);
        bf16x8 a0h, a0l, a1h, a1l;
        #pragma unroll
        for (int j = 0; j < 8; j++) {
            short h0 = f2bf(a0[j]); a0h[j] = h0; a0l[j] = f2bf(a0[j] - bf2f(h0));
            short h1 = f2bf(a1[j]); a1h[j] = h1; a1l[j] = f2bf(a1[j] - bf2f(h1));
        }
        int kb = ks * 32 + quad * 8;
        int koff = kb ^ (ln << 3);
        #pragma unroll
        for (int ct = 0; ct < 8; ct++) {
            int pos = (ct * 16 + ln) * C + koff;
            bf16x8 bh = *(bf16x8*)&Bh[pos];
            bf16x8 bl = *(bf16x8*)&Bl[pos];
            acc[0][ct] = __builtin_amdgcn_mfma_f32_16x16x32_bf16(a0h, bh, acc[0][ct], 0, 0, 0);
            acc[0][ct] = __builtin_amdgcn_mfma_f32_16x16x32_bf16(a0l, bh, acc[0][ct], 0, 0, 0);
            acc[0][ct] = __builtin_amdgcn_mfma_f32_16x16x32_bf16(a0h, bl, acc[0][ct], 0, 0, 0);
            acc[1][ct] = __builtin_amdgcn_mfma_f32_16x16x32_bf16(a1h, bh, acc[1][ct], 0, 0, 0);
            acc[1][ct] = __builtin_amdgcn_mfma_f32_16x16x32_bf16(a1l, bh, acc[1][ct], 0, 0, 0);
            acc[1][ct] = __builtin_amdgcn_mfma_f32_16x16x32_bf16(a1h, bl, acc[1][ct], 0, 0, 0);
        }
    }

    // D layout (m89): col = lane&15, row = quad*4 + reg; store half(dinv[r]*val)
    __half* H = (__half*)xwh;
    #pragma unroll
    for (int mt = 0; mt < 2; mt++) {
        int rbase = r0 + mt * 16 + quad * 4;
        #pragma unroll
        for (int reg = 0; reg < 4; reg++) {
            int r = rbase + reg;
            if (r < N) {
                float dvr = dinv[r];
                #pragma unroll
                for (int ct = 0; ct < 8; ct++) {
                    int col = ct * 16 + ln;
                    H[(size_t)r * C + col] = __float2half(acc[mt][ct][reg] * dvr);
                }
            }
        }
    }
}

// ---------------------------------------------------------------- gather v3: wave/node, quarter-wave per edge (4 edges/VMEM op)
// epack loaded 64-wide once per chunk then broadcast via __shfl (DS pipe, not VMEM).
// Each lane loads uint4 (16B = 8 cols); 16 lanes cover a row; combine = 2 shfl_xor rounds.
// Lanes >= m load pkl=0 -> weight +0.0, src 0 -> contributes exactly 0 (no branches).
__global__ __launch_bounds__(256) void k_gather(const unsigned* __restrict__ xwh,
                                                const int* __restrict__ offs,
                                                const unsigned* __restrict__ epack,
                                                const float* __restrict__ dinv,
                                                const float* __restrict__ b_conv,
                                                float* __restrict__ out, int N) {
    int t = threadIdx.x;
    int v = blockIdx.x * 4 + (t >> 6);
    int lane = t & 63;
    if (v >= N) return;
    int qh = lane >> 4;             // quarter-wave: edge slot (mod 4)
    int q  = lane & 15;             // covers cols 8q .. 8q+7
    float dv = dinv[v];

    float a[8];
    #pragma unroll
    for (int j = 0; j < 8; j++) a[j] = 0.f;
    if (qh == 0) {                  // self-loop on quarter 0 (combined later)
        uint4 sv = *(const uint4*)(xwh + (size_t)v * 64 + q * 4);
        const __half2* sh = (const __half2*)&sv;
        #pragma unroll
        for (int j = 0; j < 4; j++) {
            a[2 * j]     = __low2float(sh[j]);
            a[2 * j + 1] = __high2float(sh[j]);
        }
    }

    int e0 = offs[v], e1 = offs[v + 1];
    for (int base = e0; base < e1; base += 64) {
        int m = e1 - base; if (m > 64) m = 64;
        unsigned pkl = (lane < m) ? __builtin_nontemporal_load(&epack[base + lane]) : 0u;
        int quads = (m + 3) >> 2;
        int jj = 0;
        for (; jj + 1 < quads; jj += 2) {
            unsigned pa0 = __shfl(pkl, 4 * jj + qh);
            unsigned pa1 = __shfl(pkl, 4 * jj + 4 + qh);
            uint4 r0 = *(const uint4*)(xwh + (size_t)(pa0 & 0xFFFFu) * 64 + q * 4);
            uint4 r1 = *(const uint4*)(xwh + (size_t)(pa1 & 0xFFFFu) * 64 + q * 4);
            unsigned short h0 = (unsigned short)(pa0 >> 16);
            unsigned short h1 = (unsigned short)(pa1 >> 16);
            float nm0 = __half2float(*(__half*)&h0);
            float nm1 = __half2float(*(__half*)&h1);
            const __half2* p0 = (const __half2*)&r0;
            const __half2* p1 = (const __half2*)&r1;
            #pragma unroll
            for (int j = 0; j < 4; j++) {
                a[2 * j]     += nm0 * __low2float(p0[j]);
                a[2 * j + 1] += nm0 * __high2float(p0[j]);
                a[2 * j]     += nm1 * __low2float(p1[j]);
                a[2 * j + 1] += nm1 * __high2float(p1[j]);
            }
        }
        for (; jj < quads; jj++) {
            unsigned pa = __shfl(pkl, 4 * jj + qh);
            uint4 r = *(const uint4*)(xwh + (size_t)(pa & 0xFFFFu) * 64 + q * 4);
            unsigned short hh = (unsigned short)(pa >> 16);
            float nm = __half2float(*(__half*)&hh);
            const __half2* pr = (const __half2*)&r;
            #pragma unroll
            for (int j = 0; j < 4; j++) {
                a[2 * j]     += nm * __low2float(pr[j]);
                a[2 * j + 1] += nm * __high2float(pr[j]);
            }
        }
    }

    // combine the 4 quarter-wave partial sums (lanes q, q+16, q+32, q+48)
    #pragma unroll
    for (int j = 0; j < 8; j++) {
        a[j] += __shfl_xor(a[j], 16);
        a[j] += __shfl_xor(a[j], 32);
    }

    if (qh == 0) {
        const float* bbp = b_conv + q * 8;
        f32x4 o0, o1;
        #pragma unroll
        for (int j = 0; j < 4; j++) {
            o0[j] = a[j] * dv + bbp[j];
            o1[j] = a[4 + j] * dv + bbp[4 + j];
        }
        __builtin_nontemporal_store(o0, (f32x4*)(out + (size_t)v * C + q * 8));
        __builtin_nontemporal_store(o1, (f32x4*)(out + (size_t)v * C + q * 8 + 4));
    }
}

// ---------------------------------------------------------------- launcher (serial, 9 dispatches)
extern "C" void kernel_launch(void* const* d_in, const int* in_sizes, int n_in,
                              void* d_out, int out_size, void* d_ws, size_t ws_size,
                              hipStream_t stream) {
    const float* X      = (const float*)d_in[0];
    const float* ew     = (const float*)d_in[1];
    const float* p      = (const float*)d_in[2];
    const float* W_ih   = (const float*)d_in[3];
    const float* W_hh   = (const float*)d_in[4];
    const float* b_ih   = (const float*)d_in[5];
    const float* b_hh   = (const float*)d_in[6];
    const float* W_conv = (const float*)d_in[7];
    const float* b_conv = (const float*)d_in[8];
    const int*   ei     = (const int*)d_in[9];
    const int N = in_sizes[0] / C;
    const int E = in_sizes[1];
    float* out = (float*)d_out;
    const int NB    = (N + 255) / 256;
    const int NBIN  = (N + 255) / 256;
    const int NBLKE = (E + 2047) / 2048;

    char* w = (char*)d_ws;
    auto alloc = [&](size_t bytes) -> void* {
        void* r = (void*)w;
        w += (bytes + 255) & ~(size_t)255;
        return r;
    };
    int*   hist   = (int*)alloc(HB * 4);
    int*   nc     = (int*)alloc(256);
    size_t zbytes = (size_t)(w - (char*)d_ws);
    float* scores = (float*)alloc((size_t)N * 4);
    float* dinv   = (float*)alloc((size_t)N * 4);
    int*   offs   = (int*)alloc((size_t)(N + 1) * 4);
    int*   rh     = (int*)alloc((size_t)NBIN * NBLKE * 4);
    int*   tot    = (int*)alloc((size_t)NBIN * 4);
    unsigned long long* cand = (unsigned long long*)alloc((size_t)NS * 8);
    int*   tidx   = (int*)alloc(C * 4);
    float* gate   = (float*)alloc(C * 4);
    float* wnewT  = (float*)alloc((size_t)C * C * 4);
    unsigned long long* sorted = (unsigned long long*)alloc((size_t)E * 8);
    unsigned* epack = (unsigned*)alloc((size_t)E * 4);
    unsigned* xwh = (unsigned*)alloc((size_t)N * 64 * 4);

    hipMemsetAsync(d_ws, 0, zbytes, stream);
    k_front<<<SHB + NBLKE, 1024, 0, stream>>>(X, p, scores, hist, ei, rh, N, E, NBIN, NBLKE);
    k_filter<<<NB, 256, 0, stream>>>(scores, hist, nc, cand, N);
    k_sel<<<1, 1024, 0, stream>>>(cand, nc, p, tidx, gate);
    k_gru<<<C / 2, 256, 0, stream>>>(X, tidx, gate, W_conv, W_ih, W_hh, b_ih, b_hh, wnewT);
    k_rscanA<<<NBIN, 512, 0, stream>>>(rh, tot, NBLKE);
    k_rscat<<<NBLKE, 1024, 0, stream>>>(ei, ew, rh, tot, sorted, E, NBIN, NBLKE);
    k_bin<<<NBIN, 1024, 0, stream>>>(sorted, tot, offs, dinv, epack, N, E, NBIN);
    k_xw<<<(N + 127) / 128, 256, 0, stream>>>(X, wnewT, dinv, xwh, N);
    k_gather<<<(N + 3) / 4, 256, 0, stream>>>(xwh, offs, epack, dinv, b_conv, out, N);
}